// Round 3
// baseline (654.281 us; speedup 1.0000x reference)
//
#include <hip/hip_runtime.h>
#include <math.h>
#include <stdint.h>

#define NROWS 48000
#define KD 512
#define NE 320
#define GE 640
#define DD 384
#define OD 768
#define CB_OFF 36864000ul
#define SC_OFF 67584000ul
#define MARGIN 4e-3f

#define MT 64
#define THREADS 512
#define NBLK 750

using f16x8 = __attribute__((ext_vector_type(8))) _Float16;
using f16x4 = __attribute__((ext_vector_type(4))) _Float16;
using f32x4 = __attribute__((ext_vector_type(4))) float;

#define GLD16(gp, lp)                                                          \
    __builtin_amdgcn_global_load_lds(                                          \
        (const __attribute__((address_space(1))) uint32_t*)(gp),               \
        (__attribute__((address_space(3))) uint32_t*)(lp), 16, 0, 0)

// ---------------- split f32 -> f16 hi + f16 lo (W only, 1.3 MB) -----------
__global__ __launch_bounds__(256) void split16(const float* __restrict__ src,
                                               _Float16* __restrict__ hi,
                                               _Float16* __restrict__ lo,
                                               int n8)
{
    int i = blockIdx.x * 256 + threadIdx.x;
    if (i >= n8) return;
    float4 v0 = *((const float4*)src + 2 * (size_t)i);
    float4 v1 = *((const float4*)src + 2 * (size_t)i + 1);
    float x[8] = {v0.x, v0.y, v0.z, v0.w, v1.x, v1.y, v1.z, v1.w};
    f16x8 h, l;
    #pragma unroll
    for (int k = 0; k < 8; ++k) {
        _Float16 hh = (_Float16)x[k];
        h[k] = hh;
        l[k] = (_Float16)(x[k] - (float)hh);
    }
    *(f16x8*)(hi + (size_t)i * 8) = h;
    *(f16x8*)(lo + (size_t)i * 8) = l;
}

// ---------------- helpers -------------------------------------------------
__device__ __forceinline__ bool better(float a, int ia, float b, int ib) {
    return (a > b) || (a == b && ia < ib);
}

__device__ __forceinline__ void t2merge(float& v1, int& i1, float& v2, int& i2,
                                        float ov1, int oi1, float ov2, int oi2)
{
    if (better(ov1, oi1, v1, i1)) {
        float tv = v1; int ti = i1;
        v1 = ov1; i1 = oi1;
        if (better(ov2, oi2, tv, ti)) { v2 = ov2; i2 = oi2; }
        else                          { v2 = tv;  i2 = ti;  }
    } else if (better(ov1, oi1, v2, i2)) {
        v2 = ov1; i2 = oi1;
    }
}

__device__ __forceinline__ void bfly16_top2(float& v1, int& i1, float& v2, int& i2)
{
    #pragma unroll
    for (int m = 1; m <= 8; m <<= 1) {
        float ov1 = __shfl_xor(v1, m); int oi1 = __shfl_xor(i1, m);
        float ov2 = __shfl_xor(v2, m); int oi2 = __shfl_xor(i2, m);
        t2merge(v1, i1, v2, i2, ov1, oi1, ov2, oi2);
    }
}

// fp64 re-resolution across 64 lanes; c1,c2 codebook-local
__device__ __forceinline__ int resolve64(const float* __restrict__ X,
                                         const float* __restrict__ Wf,
                                         const float* __restrict__ bvec,
                                         const float* __restrict__ gum,
                                         int n, int hh, int c1, int c2, int typ,
                                         int lane)
{
    const float* xr = X + (size_t)n * KD;
    const float* w1 = Wf + (size_t)(hh * NE + c1) * KD;
    const float* w2 = Wf + (size_t)(hh * NE + c2) * KD;
    double d1 = 0.0, d2 = 0.0;
    #pragma unroll
    for (int j = 0; j < 8; ++j) {
        int k = lane + 64 * j;
        double xv = (double)xr[k];
        d1 += xv * (double)w1[k];
        d2 += xv * (double)w2[k];
    }
    #pragma unroll
    for (int m = 1; m <= 32; m <<= 1) {
        d1 += __shfl_xor(d1, m);
        d2 += __shfl_xor(d2, m);
    }
    d1 += (double)bvec[hh * NE + c1];
    d2 += (double)bvec[hh * NE + c2];
    if (typ) {
        const float* Ur = gum + (size_t)(2 * n + hh) * NE;
        d1 += -log(-log((double)Ur[c1] + 1e-10) + 1e-10);
        d2 += -log(-log((double)Ur[c2] + 1e-10) + 1e-10);
    }
    return (d2 > d1 || (d2 == d1 && c2 < c1)) ? c2 : c1;
}

// ---------------- fused kernel --------------------------------------------
__global__ __launch_bounds__(THREADS, 2) void fused_vq(
    const float* __restrict__ X, const float* __restrict__ Wf,
    const _Float16* __restrict__ Wh, const _Float16* __restrict__ Wl,
    const float* __restrict__ bvec, const float* __restrict__ entries,
    const float* __restrict__ gumbel, float* __restrict__ out,
    float* __restrict__ gavgp, unsigned int* __restrict__ gcnt)
{
    __shared__ float4 arena4[5632];            // 88 KB
    char* arena = (char*)arena4;
    _Float16* Ahs = (_Float16*)arena;          // [64][32]  4 KB
    _Float16* Als = (_Float16*)(arena + 4096); // 4 KB
    _Float16* Bhs = (_Float16*)(arena + 8192); // [640][32] 40 KB
    _Float16* Bls = (_Float16*)(arena + 49152);// 40 KB
    // epilogue aliases (valid after K-loop's trailing barrier)
    float*    t2     = (float*)arena;                 // [64][2][2][8] 16 KB
    int*      kpl    = (int*)(arena + 16384);         // [64][2]
    int*      kg     = (int*)(arena + 16896);
    float*    rmax   = (float*)(arena + 17408);
    float*    rsum   = (float*)(arena + 17920);       // [64][2][2]
    float*    rinv   = (float*)(arena + 18944);
    float*    s_avgp = (float*)(arena + 19456);       // [640]
    unsigned* s_cnt  = (unsigned*)(arena + 22016);    // [640]
    unsigned* nflag  = (unsigned*)(arena + 24576);
    unsigned* flags  = (unsigned*)(arena + 24580);    // [256]

    const int n0 = blockIdx.x * MT;
    const int tid = threadIdx.x;
    const int wid = tid >> 6, lane = tid & 63;
    const int fr = lane & 15, fq = lane >> 4;
    const int rg = wid >> 2, cg = wid & 3;
    const int wm = rg * 32, wn = cg * 160;
    const int h = cg >> 1, half = cg & 1;
    const int arow = tid >> 3, aq = (tid & 7) * 4;

    f32x4 acc[2][10];
    #pragma unroll
    for (int i = 0; i < 2; ++i)
        #pragma unroll
        for (int j = 0; j < 10; ++j)
            acc[i][j] = (f32x4){0.f, 0.f, 0.f, 0.f};

    // ---------------- K-loop: 3-pass split-f16 MFMA -----------------------
    for (int kk = 0; kk < 16; ++kk) {
        #pragma unroll
        for (int p = 0; p < 10; ++p) {                 // B staging via GLD16
            const bool isl = p >= 5;
            const int c = tid + (isl ? (p - 5) : p) * 512;
            const _Float16* src = (isl ? Wl : Wh) +
                (size_t)(c >> 2) * KD + kk * 32 + (c & 3) * 8;
            _Float16* dst = (isl ? Bls : Bhs) + c * 8;
            GLD16(src, dst);
        }
        // A staging: read f32, convert to hi/lo in-register
        float4 xv = *(const float4*)(X + (size_t)(n0 + arow) * KD + kk * 32 + aq);
        float xs[4] = {xv.x, xv.y, xv.z, xv.w};
        f16x4 hv, lv;
        #pragma unroll
        for (int q = 0; q < 4; ++q) {
            _Float16 hh = (_Float16)xs[q];
            hv[q] = hh;
            lv[q] = (_Float16)(xs[q] - (float)hh);
        }
        *(f16x4*)&Ahs[arow * 32 + aq] = hv;
        *(f16x4*)&Als[arow * 32 + aq] = lv;
        __syncthreads();

        f16x8 ah[2], al[2];
        #pragma unroll
        for (int i = 0; i < 2; ++i) {
            const int ro = (wm + i * 16 + fr) * 32 + fq * 8;
            ah[i] = *(const f16x8*)&Ahs[ro];
            al[i] = *(const f16x8*)&Als[ro];
        }
        #pragma unroll
        for (int j = 0; j < 10; ++j) {
            const int co = (wn + j * 16 + fr) * 32 + fq * 8;
            f16x8 bh = *(const f16x8*)&Bhs[co];
            f16x8 bl = *(const f16x8*)&Bls[co];
            #pragma unroll
            for (int i = 0; i < 2; ++i) {
                acc[i][j] = __builtin_amdgcn_mfma_f32_16x16x32_f16(ah[i], bh, acc[i][j], 0, 0, 0);
                acc[i][j] = __builtin_amdgcn_mfma_f32_16x16x32_f16(ah[i], bl, acc[i][j], 0, 0, 0);
                acc[i][j] = __builtin_amdgcn_mfma_f32_16x16x32_f16(al[i], bh, acc[i][j], 0, 0, 0);
            }
        }
        __syncthreads();
    }

    // ---------------- epilogue --------------------------------------------
    // bias add (logits now final in acc; col = wn + j*16 + fr, row = wm + i*16 + fq*4 + r)
    #pragma unroll
    for (int j = 0; j < 10; ++j) {
        float bb = bvec[wn + j * 16 + fr];
        #pragma unroll
        for (int i = 0; i < 2; ++i) {
            acc[i][j][0] += bb; acc[i][j][1] += bb;
            acc[i][j][2] += bb; acc[i][j][3] += bb;
        }
    }
    // scratch init (disjoint from t2 region written below, same epoch)
    for (int idx = tid; idx < GE; idx += THREADS) { s_avgp[idx] = 0.f; s_cnt[idx] = 0u; }
    if (tid == 0) *nflag = 0u;

    // E1: per-wave per-row top2 (plain + gumbel)
    #pragma unroll
    for (int i = 0; i < 2; ++i) {
        #pragma unroll
        for (int r = 0; r < 4; ++r) {
            const int lrow = wm + i * 16 + fq * 4 + r;
            float v1 = -3.4e38f, v2 = -3.4e38f; int i1 = 511, i2 = 511;
            #pragma unroll
            for (int j = 0; j < 10; ++j) {
                float x = acc[i][j][r];
                int e = half * 160 + j * 16 + fr;
                if (better(x, e, v1, i1)) { v2 = v1; i2 = i1; v1 = x; i1 = e; }
                else if (better(x, e, v2, i2)) { v2 = x; i2 = e; }
            }
            bfly16_top2(v1, i1, v2, i2);

            const float* Ur = gumbel + (size_t)(2 * (n0 + lrow) + h) * NE + half * 160;
            float g1 = -3.4e38f, g2 = -3.4e38f; int gi1 = 511, gi2 = 511;
            #pragma unroll
            for (int j = 0; j < 10; ++j) {
                float u = Ur[j * 16 + fr];
                float gn = -logf(-logf(u + 1e-10f) + 1e-10f);
                float x = acc[i][j][r] + gn;
                int e = half * 160 + j * 16 + fr;
                if (better(x, e, g1, gi1)) { g2 = g1; gi2 = gi1; g1 = x; gi1 = e; }
                else if (better(x, e, g2, gi2)) { g2 = x; gi2 = e; }
            }
            bfly16_top2(g1, gi1, g2, gi2);

            if (fr == 0) {
                float* d = &t2[(size_t)((lrow * 2 + h) * 2 + half) * 8];
                d[0] = v1; d[1] = (float)i1; d[2] = v2; d[3] = (float)i2;
                d[4] = g1; d[5] = (float)gi1; d[6] = g2; d[7] = (float)gi2;
            }
        }
    }
    __syncthreads();

    // E3: merge halves, decide, flag near-ties
    if (tid < 128) {
        const int lrow = tid >> 1, hh = tid & 1;
        const float* a = &t2[(size_t)((lrow * 2 + hh) * 2 + 0) * 8];
        const float* b = &t2[(size_t)((lrow * 2 + hh) * 2 + 1) * 8];
        // plain
        float v1 = a[0]; int i1 = (int)a[1]; float v2 = a[2]; int i2 = (int)a[3];
        t2merge(v1, i1, v2, i2, b[0], (int)b[1], b[2], (int)b[3]);
        kpl[lrow * 2 + hh] = i1;
        rmax[lrow * 2 + hh] = v1;
        if (v1 - v2 < MARGIN) {
            unsigned ix = atomicAdd(nflag, 1u);
            if (ix < 256u) flags[ix] = (unsigned)lrow | (hh << 8) | (0u << 9) |
                                       ((unsigned)i1 << 10) | ((unsigned)i2 << 19);
        }
        // gumbel
        float w1 = a[4]; int j1 = (int)a[5]; float w2 = a[6]; int j2 = (int)a[7];
        t2merge(w1, j1, w2, j2, b[4], (int)b[5], b[6], (int)b[7]);
        kg[lrow * 2 + hh] = j1;
        if (w1 - w2 < MARGIN) {
            unsigned ix = atomicAdd(nflag, 1u);
            if (ix < 256u) flags[ix] = (unsigned)lrow | (hh << 8) | (1u << 9) |
                                       ((unsigned)j1 << 10) | ((unsigned)j2 << 19);
        }
    }
    __syncthreads();

    // E4: rare fp64 resolves, one wave each
    {
        unsigned nf = *nflag; if (nf > 256u) nf = 256u;
        for (unsigned f = wid; f < nf; f += 8) {
            unsigned code = flags[f];
            int lrow = code & 127, hh = (code >> 8) & 1, typ = (code >> 9) & 1;
            int c1 = (code >> 10) & 511, c2 = (code >> 19) & 511;
            int w = resolve64(X, Wf, bvec, gumbel, n0 + lrow, hh, c1, c2, typ, lane);
            if (lane == 0) (typ ? kg : kpl)[lrow * 2 + hh] = w;
        }
    }
    __syncthreads();

    // E5: softmax partial sums per row per half
    #pragma unroll
    for (int i = 0; i < 2; ++i) {
        #pragma unroll
        for (int r = 0; r < 4; ++r) {
            const int lrow = wm + i * 16 + fq * 4 + r;
            float m = rmax[lrow * 2 + h];
            float s = 0.f;
            #pragma unroll
            for (int j = 0; j < 10; ++j) s += expf(acc[i][j][r] - m);
            #pragma unroll
            for (int mm = 1; mm <= 8; mm <<= 1) s += __shfl_xor(s, mm);
            if (fr == 0) rsum[(lrow * 2 + h) * 2 + half] = s;
        }
    }
    __syncthreads();

    // E6a: inverse sums + hard counts
    if (tid < 128) {
        const int lrow = tid >> 1, hh = tid & 1;
        rinv[tid] = 1.f / (rsum[tid * 2] + rsum[tid * 2 + 1]);
        atomicAdd(&s_cnt[hh * NE + kpl[tid]], 1u);
    }
    __syncthreads();

    // E6b: avg_probs accumulation
    #pragma unroll
    for (int j = 0; j < 10; ++j) {
        float pacc = 0.f;
        #pragma unroll
        for (int i = 0; i < 2; ++i) {
            #pragma unroll
            for (int r = 0; r < 4; ++r) {
                const int lrow = wm + i * 16 + fq * 4 + r;
                pacc += expf(acc[i][j][r] - rmax[lrow * 2 + h]) * rinv[lrow * 2 + h];
            }
        }
        pacc += __shfl_xor(pacc, 16);
        pacc += __shfl_xor(pacc, 32);
        if (fq == 0) atomicAdd(&s_avgp[wn + j * 16 + fr], pacc);
    }

    // E7: one-hot cb write (float4, fully coalesced)
    {
        const int row = tid >> 3, sub = tid & 7;
        const int hh = sub >> 2;
        const int kabs = kg[row * 2 + hh] + hh * NE;
        float* dst = out + CB_OFF + (size_t)(n0 + row) * GE + sub * 80;
        const int cbase = sub * 80;
        #pragma unroll
        for (int q = 0; q < 20; ++q) {
            const int c = cbase + q * 4;
            float4 v;
            v.x = (c     == kabs) ? 1.f : 0.f;
            v.y = (c + 1 == kabs) ? 1.f : 0.f;
            v.z = (c + 2 == kabs) ? 1.f : 0.f;
            v.w = (c + 3 == kabs) ? 1.f : 0.f;
            ((float4*)dst)[q] = v;
        }
    }
    // E8: quantized gather (float4)
    {
        const int row = tid >> 3, sub = tid & 7;
        const int hh = sub >> 2;
        const int d0 = sub * 96 - hh * DD;
        const float4* src = (const float4*)(entries +
            ((size_t)(hh * NE + kg[row * 2 + hh]) * DD + d0));
        float4* qd = (float4*)(out + (size_t)(n0 + row) * OD + sub * 96);
        #pragma unroll
        for (int q = 0; q < 24; ++q) qd[q] = src[q];
    }
    __syncthreads();

    // flush block stats to global
    for (int idx = tid; idx < GE; idx += THREADS) {
        float a = s_avgp[idx];
        if (a != 0.f) atomicAdd(&gavgp[idx], a);
        unsigned c = s_cnt[idx];
        if (c) atomicAdd(&gcnt[idx], c);
    }
}

// ---------------- Kernel C: perplexity scalars ----------------------------
__global__ void finalize_kernel(const float* __restrict__ gavgp,
                                const unsigned int* __restrict__ gcnt,
                                float* __restrict__ out)
{
    __shared__ double sc[GE], sp[GE];
    const int t = threadIdx.x;
    if (t < GE) {
        double hp = (double)gcnt[t] * (1.0 / 48000.0);
        sc[t] = hp * log(hp + 1e-7);
        double ap = (double)gavgp[t] * (1.0 / 48000.0);
        sp[t] = ap * log(ap + 1e-7);
    }
    __syncthreads();
    if (t == 0) {
        double c0 = 0, c1 = 0, p0 = 0, p1 = 0;
        for (int e = 0; e < NE; ++e) { c0 += sc[e]; p0 += sp[e]; }
        for (int e = NE; e < GE; ++e) { c1 += sc[e]; p1 += sp[e]; }
        out[SC_OFF]     = (float)(exp(-c0) + exp(-c1));
        out[SC_OFF + 1] = (float)(exp(-p0) + exp(-p1));
    }
}

// ---------------- launch --------------------------------------------------
extern "C" void kernel_launch(void* const* d_in, const int* in_sizes, int n_in,
                              void* d_out, int out_size, void* d_ws, size_t ws_size,
                              hipStream_t stream)
{
    const float* X       = (const float*)d_in[0];
    const float* Wf      = (const float*)d_in[1];
    const float* bvec    = (const float*)d_in[2];
    const float* entries = (const float*)d_in[3];
    const float* gumbel  = (const float*)d_in[4];
    float* out = (float*)d_out;

    float* gavgp = (float*)d_ws;                                   // 2560 B
    unsigned int* gcnt = (unsigned int*)((char*)d_ws + 2560);      // 2560 B
    _Float16* Wh = (_Float16*)((char*)d_ws + 8192);                // 640 KB
    _Float16* Wl = (_Float16*)((char*)d_ws + 8192 + 655360);       // 640 KB

    hipMemsetAsync(d_ws, 0, 8192, stream);
    split16<<<160, 256, 0, stream>>>(Wf, Wh, Wl, 40960);           // 640*512/8
    fused_vq<<<NBLK, THREADS, 0, stream>>>(X, Wf, Wh, Wl, bvec, entries,
                                           gumbel, out, gavgp, gcnt);
    finalize_kernel<<<1, 640, 0, stream>>>(gavgp, gcnt, out);
}

// Round 4
// 622.507 us; speedup vs baseline: 1.0510x; 1.0510x over previous
//
#include <hip/hip_runtime.h>
#include <math.h>
#include <stdint.h>

#define NROWS 48000
#define KD 512
#define NE 320
#define GE 640
#define DD 384
#define OD 768
#define CB_OFF 36864000ul
#define SC_OFF 67584000ul
#define MARGIN 4e-3f

#define MT 64
#define THREADS 512
#define NBLK 750

using f16x8 = __attribute__((ext_vector_type(8))) _Float16;
using f16x4 = __attribute__((ext_vector_type(4))) _Float16;
using f32x4 = __attribute__((ext_vector_type(4))) float;

// ---------------- split f32 -> f16 hi + f16 lo (W only, 1.3 MB) -----------
__global__ __launch_bounds__(256) void split16(const float* __restrict__ src,
                                               _Float16* __restrict__ hi,
                                               _Float16* __restrict__ lo,
                                               int n8)
{
    int i = blockIdx.x * 256 + threadIdx.x;
    if (i >= n8) return;
    float4 v0 = *((const float4*)src + 2 * (size_t)i);
    float4 v1 = *((const float4*)src + 2 * (size_t)i + 1);
    float x[8] = {v0.x, v0.y, v0.z, v0.w, v1.x, v1.y, v1.z, v1.w};
    f16x8 h, l;
    #pragma unroll
    for (int k = 0; k < 8; ++k) {
        _Float16 hh = (_Float16)x[k];
        h[k] = hh;
        l[k] = (_Float16)(x[k] - (float)hh);
    }
    *(f16x8*)(hi + (size_t)i * 8) = h;
    *(f16x8*)(lo + (size_t)i * 8) = l;
}

// ---------------- helpers -------------------------------------------------
__device__ __forceinline__ bool better(float a, int ia, float b, int ib) {
    return (a > b) || (a == b && ia < ib);
}

__device__ __forceinline__ void t2merge(float& v1, int& i1, float& v2, int& i2,
                                        float ov1, int oi1, float ov2, int oi2)
{
    if (better(ov1, oi1, v1, i1)) {
        float tv = v1; int ti = i1;
        v1 = ov1; i1 = oi1;
        if (better(ov2, oi2, tv, ti)) { v2 = ov2; i2 = oi2; }
        else                          { v2 = tv;  i2 = ti;  }
    } else if (better(ov1, oi1, v2, i2)) {
        v2 = ov1; i2 = oi1;
    }
}

__device__ __forceinline__ void bfly16_top2(float& v1, int& i1, float& v2, int& i2)
{
    #pragma unroll
    for (int m = 1; m <= 8; m <<= 1) {
        float ov1 = __shfl_xor(v1, m); int oi1 = __shfl_xor(i1, m);
        float ov2 = __shfl_xor(v2, m); int oi2 = __shfl_xor(i2, m);
        t2merge(v1, i1, v2, i2, ov1, oi1, ov2, oi2);
    }
}

// fp64 re-resolution across 64 lanes; c1,c2 codebook-local
__device__ __forceinline__ int resolve64(const float* __restrict__ X,
                                         const float* __restrict__ Wf,
                                         const float* __restrict__ bvec,
                                         const float* __restrict__ gum,
                                         int n, int hh, int c1, int c2, int typ,
                                         int lane)
{
    const float* xr = X + (size_t)n * KD;
    const float* w1 = Wf + (size_t)(hh * NE + c1) * KD;
    const float* w2 = Wf + (size_t)(hh * NE + c2) * KD;
    double d1 = 0.0, d2 = 0.0;
    #pragma unroll
    for (int j = 0; j < 8; ++j) {
        int k = lane + 64 * j;
        double xv = (double)xr[k];
        d1 += xv * (double)w1[k];
        d2 += xv * (double)w2[k];
    }
    #pragma unroll
    for (int m = 1; m <= 32; m <<= 1) {
        d1 += __shfl_xor(d1, m);
        d2 += __shfl_xor(d2, m);
    }
    d1 += (double)bvec[hh * NE + c1];
    d2 += (double)bvec[hh * NE + c2];
    if (typ) {
        const float* Ur = gum + (size_t)(2 * n + hh) * NE;
        d1 += -log(-log((double)Ur[c1] + 1e-10) + 1e-10);
        d2 += -log(-log((double)Ur[c2] + 1e-10) + 1e-10);
    }
    return (d2 > d1 || (d2 == d1 && c2 < c1)) ? c2 : c1;
}

// ---------------- fused kernel --------------------------------------------
// LDS arena 17.9 KB -> 2 blocks/CU (VGPR<=128 via launch_bounds(512,4)).
// B fragments come straight from L2-resident Wh/Wl into registers (no LDS,
// no global_load_lds). Only the 8 KB A tile is staged through LDS.
__global__ __launch_bounds__(THREADS, 4) void fused_vq(
    const float* __restrict__ X, const float* __restrict__ Wf,
    const _Float16* __restrict__ Wh, const _Float16* __restrict__ Wl,
    const float* __restrict__ bvec, const float* __restrict__ entries,
    const float* __restrict__ gumbel, float* __restrict__ out,
    float* __restrict__ gavgp, unsigned int* __restrict__ gcnt)
{
    __shared__ float4 arena4[1120];            // 17920 B
    char* arena = (char*)arena4;
    _Float16* Ahs = (_Float16*)arena;          // [64][32] swizzled, 4 KB
    _Float16* Als = (_Float16*)(arena + 4096); // 4 KB
    // epilogue aliases (valid after K-loop's trailing barrier)
    float*    t2     = (float*)arena;                 // [64][2][2][8] 8 KB
    int*      kpl    = (int*)(arena + 8192);          // [64][2]
    int*      kg     = (int*)(arena + 8704);
    float*    rmax   = (float*)(arena + 9216);
    float*    rsum   = (float*)(arena + 9728);        // [64][2][2]
    float*    rinv   = (float*)(arena + 10752);
    float*    s_avgp = (float*)(arena + 11264);       // [640]
    unsigned* s_cnt  = (unsigned*)(arena + 13824);    // [640]
    unsigned* nflag  = (unsigned*)(arena + 16384);
    unsigned* flags  = (unsigned*)(arena + 16388);    // [256]

    const int n0 = blockIdx.x * MT;
    const int tid = threadIdx.x;
    const int wid = tid >> 6, lane = tid & 63;
    const int fr = lane & 15, fq = lane >> 4;
    const int rg = wid >> 2, cg = wid & 3;
    const int wm = rg * 32, wn = cg * 160;
    const int h = cg >> 1, half = cg & 1;
    const int arow = tid >> 3, aq = (tid & 7) * 4;   // A staging: row, k-start

    f32x4 acc[2][10];
    #pragma unroll
    for (int i = 0; i < 2; ++i)
        #pragma unroll
        for (int j = 0; j < 10; ++j)
            acc[i][j] = (f32x4){0.f, 0.f, 0.f, 0.f};

    // A-staging swizzled LDS index (halves): row*32 + ((chunk^ (row&3))<<3) + (aq&4)
    const int awr = arow * 32 + ((((aq >> 3) ^ (arow & 3)) << 3)) + (aq & 4);
    // A-fragment read indices
    const int ar0 = wm + fr,      ai0 = ar0 * 32 + ((fq ^ (ar0 & 3)) << 3);
    const int ar1 = wm + 16 + fr, ai1 = ar1 * 32 + ((fq ^ (ar1 & 3)) << 3);

    // ---------------- K-loop: 3-pass split-f16 MFMA -----------------------
    for (int kk = 0; kk < 16; ++kk) {
        // stage A: read f32, convert to hi/lo in-register, swizzled LDS write
        float4 xv = *(const float4*)(X + (size_t)(n0 + arow) * KD + kk * 32 + aq);
        float xs[4] = {xv.x, xv.y, xv.z, xv.w};
        f16x4 hv, lv;
        #pragma unroll
        for (int q = 0; q < 4; ++q) {
            _Float16 hh = (_Float16)xs[q];
            hv[q] = hh;
            lv[q] = (_Float16)(xs[q] - (float)hh);
        }
        *(f16x4*)&Ahs[awr] = hv;
        *(f16x4*)&Als[awr] = lv;
        __syncthreads();

        f16x8 ah0 = *(const f16x8*)&Ahs[ai0];
        f16x8 al0 = *(const f16x8*)&Als[ai0];
        f16x8 ah1 = *(const f16x8*)&Ahs[ai1];
        f16x8 al1 = *(const f16x8*)&Als[ai1];

        #pragma unroll
        for (int j = 0; j < 10; ++j) {
            const size_t bo = (size_t)(wn + j * 16 + fr) * KD + kk * 32 + fq * 8;
            f16x8 bh = *(const f16x8*)(Wh + bo);
            f16x8 bl = *(const f16x8*)(Wl + bo);
            acc[0][j] = __builtin_amdgcn_mfma_f32_16x16x32_f16(ah0, bh, acc[0][j], 0, 0, 0);
            acc[1][j] = __builtin_amdgcn_mfma_f32_16x16x32_f16(ah1, bh, acc[1][j], 0, 0, 0);
            acc[0][j] = __builtin_amdgcn_mfma_f32_16x16x32_f16(ah0, bl, acc[0][j], 0, 0, 0);
            acc[1][j] = __builtin_amdgcn_mfma_f32_16x16x32_f16(ah1, bl, acc[1][j], 0, 0, 0);
            acc[0][j] = __builtin_amdgcn_mfma_f32_16x16x32_f16(al0, bh, acc[0][j], 0, 0, 0);
            acc[1][j] = __builtin_amdgcn_mfma_f32_16x16x32_f16(al1, bh, acc[1][j], 0, 0, 0);
        }
        __syncthreads();
    }

    // ---------------- epilogue --------------------------------------------
    // bias add (col = wn + j*16 + fr, row = wm + i*16 + fq*4 + r)
    #pragma unroll
    for (int j = 0; j < 10; ++j) {
        float bb = bvec[wn + j * 16 + fr];
        #pragma unroll
        for (int i = 0; i < 2; ++i) {
            acc[i][j][0] += bb; acc[i][j][1] += bb;
            acc[i][j][2] += bb; acc[i][j][3] += bb;
        }
    }
    for (int idx = tid; idx < GE; idx += THREADS) { s_avgp[idx] = 0.f; s_cnt[idx] = 0u; }
    if (tid == 0) *nflag = 0u;

    // E1: per-wave per-row top2 (plain + gumbel)
    #pragma unroll
    for (int i = 0; i < 2; ++i) {
        #pragma unroll
        for (int r = 0; r < 4; ++r) {
            const int lrow = wm + i * 16 + fq * 4 + r;
            float v1 = -3.4e38f, v2 = -3.4e38f; int i1 = 511, i2 = 511;
            #pragma unroll
            for (int j = 0; j < 10; ++j) {
                float x = acc[i][j][r];
                int e = half * 160 + j * 16 + fr;
                if (better(x, e, v1, i1)) { v2 = v1; i2 = i1; v1 = x; i1 = e; }
                else if (better(x, e, v2, i2)) { v2 = x; i2 = e; }
            }
            bfly16_top2(v1, i1, v2, i2);

            const float* Ur = gumbel + (size_t)(2 * (n0 + lrow) + h) * NE + half * 160;
            float g1 = -3.4e38f, g2 = -3.4e38f; int gi1 = 511, gi2 = 511;
            #pragma unroll
            for (int j = 0; j < 10; ++j) {
                float u = Ur[j * 16 + fr];
                float gn = -logf(-logf(u + 1e-10f) + 1e-10f);
                float x = acc[i][j][r] + gn;
                int e = half * 160 + j * 16 + fr;
                if (better(x, e, g1, gi1)) { g2 = g1; gi2 = gi1; g1 = x; gi1 = e; }
                else if (better(x, e, g2, gi2)) { g2 = x; gi2 = e; }
            }
            bfly16_top2(g1, gi1, g2, gi2);

            if (fr == 0) {
                float* d = &t2[(size_t)((lrow * 2 + h) * 2 + half) * 8];
                d[0] = v1; d[1] = (float)i1; d[2] = v2; d[3] = (float)i2;
                d[4] = g1; d[5] = (float)gi1; d[6] = g2; d[7] = (float)gi2;
            }
        }
    }
    __syncthreads();

    // E3: merge halves, decide, flag near-ties
    if (tid < 128) {
        const int lrow = tid >> 1, hh = tid & 1;
        const float* a = &t2[(size_t)((lrow * 2 + hh) * 2 + 0) * 8];
        const float* b = &t2[(size_t)((lrow * 2 + hh) * 2 + 1) * 8];
        float v1 = a[0]; int i1 = (int)a[1]; float v2 = a[2]; int i2 = (int)a[3];
        t2merge(v1, i1, v2, i2, b[0], (int)b[1], b[2], (int)b[3]);
        kpl[lrow * 2 + hh] = i1;
        rmax[lrow * 2 + hh] = v1;
        if (v1 - v2 < MARGIN) {
            unsigned ix = atomicAdd(nflag, 1u);
            if (ix < 256u) flags[ix] = (unsigned)lrow | (hh << 8) | (0u << 9) |
                                       ((unsigned)i1 << 10) | ((unsigned)i2 << 19);
        }
        float w1 = a[4]; int j1 = (int)a[5]; float w2 = a[6]; int j2 = (int)a[7];
        t2merge(w1, j1, w2, j2, b[4], (int)b[5], b[6], (int)b[7]);
        kg[lrow * 2 + hh] = j1;
        if (w1 - w2 < MARGIN) {
            unsigned ix = atomicAdd(nflag, 1u);
            if (ix < 256u) flags[ix] = (unsigned)lrow | (hh << 8) | (1u << 9) |
                                       ((unsigned)j1 << 10) | ((unsigned)j2 << 19);
        }
    }
    __syncthreads();

    // E4: rare fp64 resolves, one wave each
    {
        unsigned nf = *nflag; if (nf > 256u) nf = 256u;
        for (unsigned f = wid; f < nf; f += 8) {
            unsigned code = flags[f];
            int lrow = code & 127, hh = (code >> 8) & 1, typ = (code >> 9) & 1;
            int c1 = (code >> 10) & 511, c2 = (code >> 19) & 511;
            int w = resolve64(X, Wf, bvec, gumbel, n0 + lrow, hh, c1, c2, typ, lane);
            if (lane == 0) (typ ? kg : kpl)[lrow * 2 + hh] = w;
        }
    }
    __syncthreads();

    // E5: softmax partial sums per row per half
    #pragma unroll
    for (int i = 0; i < 2; ++i) {
        #pragma unroll
        for (int r = 0; r < 4; ++r) {
            const int lrow = wm + i * 16 + fq * 4 + r;
            float m = rmax[lrow * 2 + h];
            float s = 0.f;
            #pragma unroll
            for (int j = 0; j < 10; ++j) s += expf(acc[i][j][r] - m);
            #pragma unroll
            for (int mm = 1; mm <= 8; mm <<= 1) s += __shfl_xor(s, mm);
            if (fr == 0) rsum[(lrow * 2 + h) * 2 + half] = s;
        }
    }
    __syncthreads();

    // E6a: inverse sums + hard counts
    if (tid < 128) {
        const int lrow = tid >> 1, hh = tid & 1;
        rinv[tid] = 1.f / (rsum[tid * 2] + rsum[tid * 2 + 1]);
        atomicAdd(&s_cnt[hh * NE + kpl[tid]], 1u);
    }
    __syncthreads();

    // E6b: avg_probs accumulation
    #pragma unroll
    for (int j = 0; j < 10; ++j) {
        float pacc = 0.f;
        #pragma unroll
        for (int i = 0; i < 2; ++i) {
            #pragma unroll
            for (int r = 0; r < 4; ++r) {
                const int lrow = wm + i * 16 + fq * 4 + r;
                pacc += expf(acc[i][j][r] - rmax[lrow * 2 + h]) * rinv[lrow * 2 + h];
            }
        }
        pacc += __shfl_xor(pacc, 16);
        pacc += __shfl_xor(pacc, 32);
        if (fq == 0) atomicAdd(&s_avgp[wn + j * 16 + fr], pacc);
    }

    // E7: one-hot cb write (float4, fully coalesced)
    {
        const int row = tid >> 3, sub = tid & 7;
        const int hh = sub >> 2;
        const int kabs = kg[row * 2 + hh] + hh * NE;
        float* dst = out + CB_OFF + (size_t)(n0 + row) * GE + sub * 80;
        const int cbase = sub * 80;
        #pragma unroll
        for (int q = 0; q < 20; ++q) {
            const int c = cbase + q * 4;
            float4 v;
            v.x = (c     == kabs) ? 1.f : 0.f;
            v.y = (c + 1 == kabs) ? 1.f : 0.f;
            v.z = (c + 2 == kabs) ? 1.f : 0.f;
            v.w = (c + 3 == kabs) ? 1.f : 0.f;
            ((float4*)dst)[q] = v;
        }
    }
    // E8: quantized gather (float4)
    {
        const int row = tid >> 3, sub = tid & 7;
        const int hh = sub >> 2;
        const int d0 = sub * 96 - hh * DD;
        const float4* src = (const float4*)(entries +
            ((size_t)(hh * NE + kg[row * 2 + hh]) * DD + d0));
        float4* qd = (float4*)(out + (size_t)(n0 + row) * OD + sub * 96);
        #pragma unroll
        for (int q = 0; q < 24; ++q) qd[q] = src[q];
    }
    __syncthreads();

    // flush block stats to global
    for (int idx = tid; idx < GE; idx += THREADS) {
        float a = s_avgp[idx];
        if (a != 0.f) atomicAdd(&gavgp[idx], a);
        unsigned c = s_cnt[idx];
        if (c) atomicAdd(&gcnt[idx], c);
    }
}

// ---------------- Kernel C: perplexity scalars ----------------------------
__global__ void finalize_kernel(const float* __restrict__ gavgp,
                                const unsigned int* __restrict__ gcnt,
                                float* __restrict__ out)
{
    __shared__ double sc[GE], sp[GE];
    const int t = threadIdx.x;
    if (t < GE) {
        double hp = (double)gcnt[t] * (1.0 / 48000.0);
        sc[t] = hp * log(hp + 1e-7);
        double ap = (double)gavgp[t] * (1.0 / 48000.0);
        sp[t] = ap * log(ap + 1e-7);
    }
    __syncthreads();
    if (t == 0) {
        double c0 = 0, c1 = 0, p0 = 0, p1 = 0;
        for (int e = 0; e < NE; ++e) { c0 += sc[e]; p0 += sp[e]; }
        for (int e = NE; e < GE; ++e) { c1 += sc[e]; p1 += sp[e]; }
        out[SC_OFF]     = (float)(exp(-c0) + exp(-c1));
        out[SC_OFF + 1] = (float)(exp(-p0) + exp(-p1));
    }
}

// ---------------- launch --------------------------------------------------
extern "C" void kernel_launch(void* const* d_in, const int* in_sizes, int n_in,
                              void* d_out, int out_size, void* d_ws, size_t ws_size,
                              hipStream_t stream)
{
    const float* X       = (const float*)d_in[0];
    const float* Wf      = (const float*)d_in[1];
    const float* bvec    = (const float*)d_in[2];
    const float* entries = (const float*)d_in[3];
    const float* gumbel  = (const float*)d_in[4];
    float* out = (float*)d_out;

    float* gavgp = (float*)d_ws;                                   // 2560 B
    unsigned int* gcnt = (unsigned int*)((char*)d_ws + 2560);      // 2560 B
    _Float16* Wh = (_Float16*)((char*)d_ws + 8192);                // 640 KB
    _Float16* Wl = (_Float16*)((char*)d_ws + 8192 + 655360);       // 640 KB

    hipMemsetAsync(d_ws, 0, 8192, stream);
    split16<<<160, 256, 0, stream>>>(Wf, Wh, Wl, 40960);           // 640*512/8
    fused_vq<<<NBLK, THREADS, 0, stream>>>(X, Wf, Wh, Wl, bvec, entries,
                                           gumbel, out, gavgp, gcnt);
    finalize_kernel<<<1, 640, 0, stream>>>(gavgp, gcnt, out);
}

// Round 5
// 274.747 us; speedup vs baseline: 2.3814x; 2.2657x over previous
//
#include <hip/hip_runtime.h>
#include <math.h>
#include <stdint.h>

#define NROWS 48000
#define KDIM 512
#define NE 320
#define GE 640
#define DDIM 384
#define ODIM 768
#define CB_OFF 36864000ul
#define SC_OFF 67584000ul
#define MARGIN 4e-3f

using f16x8 = __attribute__((ext_vector_type(8))) _Float16;
using f32x4 = __attribute__((ext_vector_type(4))) float;

#define GLD16(gp, lp)                                                          \
    __builtin_amdgcn_global_load_lds(                                          \
        (const __attribute__((address_space(1))) uint32_t*)(gp),               \
        (__attribute__((address_space(3))) uint32_t*)(lp), 16, 0, 0)

// ---------------- split f32 -> f16 hi + f16 lo (W only, 1.3 MB) -----------
__global__ __launch_bounds__(256) void split16(const float* __restrict__ src,
                                               _Float16* __restrict__ hi,
                                               _Float16* __restrict__ lo,
                                               int n8)
{
    int i = blockIdx.x * 256 + threadIdx.x;
    if (i >= n8) return;
    float4 v0 = *((const float4*)src + 2 * (size_t)i);
    float4 v1 = *((const float4*)src + 2 * (size_t)i + 1);
    float x[8] = {v0.x, v0.y, v0.z, v0.w, v1.x, v1.y, v1.z, v1.w};
    f16x8 h, l;
    #pragma unroll
    for (int k = 0; k < 8; ++k) {
        _Float16 hh = (_Float16)x[k];
        h[k] = hh;
        l[k] = (_Float16)(x[k] - (float)hh);
    }
    *(f16x8*)(hi + (size_t)i * 8) = h;
    *(f16x8*)(lo + (size_t)i * 8) = l;
}

// ---------------- Kernel A: logits = X @ W^T + b via split-f16 MFMA --------
// A-side: X read as f32 (coalesced), converted to hi/lo in-register, staged
// to LDS with ds_write_b128. B-side: GLD16 from pre-split Wh/Wl (L2-resident).
__global__ __launch_bounds__(256) void gemm_cvt(
    const float* __restrict__ X,
    const _Float16* __restrict__ Wh, const _Float16* __restrict__ Wl,
    const float* __restrict__ bvec, float* __restrict__ Lout)
{
    __shared__ _Float16 lds[16384];             // 32 KB: Ah|Al|Bh|Bl, each [128][32]
    _Float16* Ahs = lds;
    _Float16* Als = lds + 4096;
    _Float16* Bhs = lds + 8192;
    _Float16* Bls = lds + 12288;

    // bijective XCD swizzle (nwg=1875): q8=234, r8=3
    const int bid = blockIdx.x;
    const int q8 = 1875 / 8, r8 = 1875 % 8;
    const int xcd = bid & 7, wi = bid >> 3;
    const int wg = (xcd < r8 ? xcd * (q8 + 1) : r8 * (q8 + 1) + (xcd - r8) * q8) + wi;
    const int bm = wg / 5, bn = wg % 5;

    const int tid = threadIdx.x;
    const int wid = tid >> 6, lane = tid & 63;
    const int fr = lane & 15, fq = lane >> 4;
    const int wm = (wid >> 1) * 64, wn = (wid & 1) * 64;

    const float*     Ag  = X  + (size_t)(bm * 128) * KDIM;
    const _Float16*  Bhg = Wh + (size_t)(bn * 128) * KDIM;
    const _Float16*  Blg = Wl + (size_t)(bn * 128) * KDIM;

    f32x4 acc[4][4];
    #pragma unroll
    for (int i = 0; i < 4; ++i)
        #pragma unroll
        for (int j = 0; j < 4; ++j)
            acc[i][j] = (f32x4){0.f, 0.f, 0.f, 0.f};

    for (int kk = 0; kk < 16; ++kk) {
        const int kh = kk * 32;
        // B staging via GLD16 (4 per lane)
        #pragma unroll
        for (int q = 0; q < 2; ++q) {
            const int c = wid * 2 + q;                    // chunk: 16 rows
            const int srow = lane >> 2, sc8 = (lane & 3) * 8;
            const size_t go = (size_t)(c * 16 + srow) * KDIM + kh + sc8;
            GLD16(Bhg + go, Bhs + c * 512);
            GLD16(Blg + go, Bls + c * 512);
        }
        // A staging: f32 -> hi/lo in-register -> LDS
        #pragma unroll
        for (int c = 0; c < 2; ++c) {
            const int idx8 = c * 256 + tid;
            const int row = idx8 >> 2, k8 = (idx8 & 3) * 8;
            const float4* xp = (const float4*)(Ag + (size_t)row * KDIM + kh + k8);
            float4 v0 = xp[0], v1 = xp[1];
            float xs[8] = {v0.x, v0.y, v0.z, v0.w, v1.x, v1.y, v1.z, v1.w};
            f16x8 h, l;
            #pragma unroll
            for (int q = 0; q < 8; ++q) {
                _Float16 hh = (_Float16)xs[q];
                h[q] = hh;
                l[q] = (_Float16)(xs[q] - (float)hh);
            }
            *(f16x8*)&Ahs[row * 32 + k8] = h;
            *(f16x8*)&Als[row * 32 + k8] = l;
        }
        __syncthreads();

        f16x8 ah[4], al[4], bh[4], bl[4];
        #pragma unroll
        for (int i = 0; i < 4; ++i) {
            const int ro = (wm + i * 16 + fr) * 32 + fq * 8;
            ah[i] = *(const f16x8*)&Ahs[ro];
            al[i] = *(const f16x8*)&Als[ro];
            const int co = (wn + i * 16 + fr) * 32 + fq * 8;
            bh[i] = *(const f16x8*)&Bhs[co];
            bl[i] = *(const f16x8*)&Bls[co];
        }
        #pragma unroll
        for (int i = 0; i < 4; ++i)
            #pragma unroll
            for (int j = 0; j < 4; ++j) {
                acc[i][j] = __builtin_amdgcn_mfma_f32_16x16x32_f16(ah[i], bh[j], acc[i][j], 0, 0, 0);
                acc[i][j] = __builtin_amdgcn_mfma_f32_16x16x32_f16(ah[i], bl[j], acc[i][j], 0, 0, 0);
                acc[i][j] = __builtin_amdgcn_mfma_f32_16x16x32_f16(al[i], bh[j], acc[i][j], 0, 0, 0);
            }
        __syncthreads();
    }

    // C/D layout: col = lane&15, row = (lane>>4)*4 + reg   [m89-verified]
    #pragma unroll
    for (int i = 0; i < 4; ++i) {
        #pragma unroll
        for (int r = 0; r < 4; ++r) {
            const int m = bm * 128 + wm + i * 16 + fq * 4 + r;
            float* orow = Lout + (size_t)m * GE + bn * 128 + wn;
            #pragma unroll
            for (int j = 0; j < 4; ++j) {
                const int n = bn * 128 + wn + j * 16 + fr;
                orow[j * 16 + fr] = acc[i][j][r] + bvec[n];
            }
        }
    }
}

// ---------------- Kernel B: per-row epilogue (round-2 proven) -------------
__device__ __forceinline__ bool better(float a, int ia, float b, int ib) {
    return (a > b) || (a == b && ia < ib);
}

__device__ __forceinline__ void top2_half(const float* v, int il,
                                          float& v1, int& i1, float& v2, int& i2)
{
    v1 = -3.4e38f; i1 = 0x7fffffff;
    v2 = -3.4e38f; i2 = 0x7fffffff;
    #pragma unroll
    for (int i = 0; i < 10; ++i) {
        int e = il + 32 * i;
        float x = v[i];
        if (better(x, e, v1, i1)) { v2 = v1; i2 = i1; v1 = x; i1 = e; }
        else if (better(x, e, v2, i2)) { v2 = x; i2 = e; }
    }
    #pragma unroll
    for (int m = 1; m <= 16; m <<= 1) {
        float ov1 = __shfl_xor(v1, m); int oi1 = __shfl_xor(i1, m);
        float ov2 = __shfl_xor(v2, m); int oi2 = __shfl_xor(i2, m);
        float lv; int li;
        if (better(ov1, oi1, v1, i1)) { lv = v1; li = i1; v1 = ov1; i1 = oi1; }
        else { lv = ov1; li = oi1; }
        if (better(lv, li, v2, i2)) { v2 = lv; i2 = li; }
        if (better(ov2, oi2, v2, i2)) { v2 = ov2; i2 = oi2; }
    }
}

__device__ int resolve2(const float* __restrict__ X, const float* __restrict__ W,
                        const float* __restrict__ bvec, const float* __restrict__ Urow,
                        int n, int h, int c1, int c2, bool gum, int il)
{
    const float* xr = X + (size_t)n * KDIM;
    const float* w1 = W + (size_t)(h * NE + c1) * KDIM;
    const float* w2 = W + (size_t)(h * NE + c2) * KDIM;
    double d1 = 0.0, d2 = 0.0;
    #pragma unroll
    for (int j = 0; j < 16; ++j) {
        int k = il + 32 * j;
        double xv = (double)xr[k];
        d1 += xv * (double)w1[k];
        d2 += xv * (double)w2[k];
    }
    #pragma unroll
    for (int m = 1; m <= 16; m <<= 1) {
        d1 += __shfl_xor(d1, m);
        d2 += __shfl_xor(d2, m);
    }
    d1 += (double)bvec[h * NE + c1];
    d2 += (double)bvec[h * NE + c2];
    if (gum) {
        d1 += -log(-log((double)Urow[c1] + 1e-10) + 1e-10);
        d2 += -log(-log((double)Urow[c2] + 1e-10) + 1e-10);
    }
    return (d2 > d1 || (d2 == d1 && c2 < c1)) ? c2 : c1;
}

__global__ __launch_bounds__(256) void epilogue_kernel(
    const float* __restrict__ X, const float* __restrict__ W,
    const float* __restrict__ bvec, const float* __restrict__ entries,
    const float* __restrict__ gumbel, float* __restrict__ out,
    float* __restrict__ gavgp, unsigned int* __restrict__ gcnt)
{
    __shared__ float s_avgp[GE];
    __shared__ unsigned int s_cnt[GE];
    const int tid = threadIdx.x;
    for (int i = tid; i < GE; i += 256) { s_avgp[i] = 0.f; s_cnt[i] = 0u; }
    __syncthreads();

    const int wave = tid >> 6, lane = tid & 63;
    const int h = lane >> 5, il = lane & 31;

    float accp[10];
    #pragma unroll
    for (int i = 0; i < 10; ++i) accp[i] = 0.f;

    float* cb = out + CB_OFF;

    for (int rr = 0; rr < 8; ++rr) {
        const int n = blockIdx.x * 32 + wave * 8 + rr;
        float* Lrow = cb + (size_t)n * GE + h * NE;
        const float* Urow = gumbel + (size_t)(2 * n + h) * NE;

        float lg[10], zg[10];
        #pragma unroll
        for (int i = 0; i < 10; ++i) {
            int e = il + 32 * i;
            lg[i] = Lrow[e];
            float gn = -logf(-logf(Urow[e] + 1e-10f) + 1e-10f);
            zg[i] = lg[i] + gn;
        }

        float pv1, pv2; int pi1, pi2;
        top2_half(lg, il, pv1, pi1, pv2, pi2);
        float gv1, gv2; int gi1, gi2;
        top2_half(zg, il, gv1, gi1, gv2, gi2);

        int k_plain = pi1;
        if (pv1 - pv2 < MARGIN)
            k_plain = resolve2(X, W, bvec, Urow, n, h, pi1, pi2, false, il);
        int k_g = gi1;
        if (gv1 - gv2 < MARGIN)
            k_g = resolve2(X, W, bvec, Urow, n, h, gi1, gi2, true, il);

        float s = 0.f, ex[10];
        #pragma unroll
        for (int i = 0; i < 10; ++i) { ex[i] = expf(lg[i] - pv1); s += ex[i]; }
        #pragma unroll
        for (int m = 1; m <= 16; m <<= 1) s += __shfl_xor(s, m);
        float inv = 1.f / s;
        #pragma unroll
        for (int i = 0; i < 10; ++i) accp[i] += ex[i] * inv;

        if (il == 0) atomicAdd(&s_cnt[h * NE + k_plain], 1u);

        #pragma unroll
        for (int i = 0; i < 10; ++i) {
            int e = il + 32 * i;
            Lrow[e] = (e == k_g) ? 1.f : 0.f;
        }
        const float* ent = entries + (size_t)(h * NE + k_g) * DDIM;
        float* qrow = out + (size_t)n * ODIM + h * DDIM;
        #pragma unroll
        for (int j = 0; j < 12; ++j) {
            int d = il + 32 * j;
            qrow[d] = ent[d];
        }
    }

    #pragma unroll
    for (int i = 0; i < 10; ++i)
        atomicAdd(&s_avgp[h * NE + il + 32 * i], accp[i]);
    __syncthreads();
    for (int i = tid; i < GE; i += 256) {
        atomicAdd(&gavgp[i], s_avgp[i]);
        unsigned int c = s_cnt[i];
        if (c) atomicAdd(&gcnt[i], c);
    }
}

// ---------------- Kernel C: perplexity scalars ----------------------------
__global__ void finalize_kernel(const float* __restrict__ gavgp,
                                const unsigned int* __restrict__ gcnt,
                                float* __restrict__ out)
{
    __shared__ double sc[GE], sp[GE];
    const int t = threadIdx.x;
    if (t < GE) {
        double hp = (double)gcnt[t] * (1.0 / 48000.0);
        sc[t] = hp * log(hp + 1e-7);
        double ap = (double)gavgp[t] * (1.0 / 48000.0);
        sp[t] = ap * log(ap + 1e-7);
    }
    __syncthreads();
    if (t == 0) {
        double c0 = 0, c1 = 0, p0 = 0, p1 = 0;
        for (int e = 0; e < NE; ++e) { c0 += sc[e]; p0 += sp[e]; }
        for (int e = NE; e < GE; ++e) { c1 += sc[e]; p1 += sp[e]; }
        out[SC_OFF]     = (float)(exp(-c0) + exp(-c1));
        out[SC_OFF + 1] = (float)(exp(-p0) + exp(-p1));
    }
}

// ---------------- launch --------------------------------------------------
extern "C" void kernel_launch(void* const* d_in, const int* in_sizes, int n_in,
                              void* d_out, int out_size, void* d_ws, size_t ws_size,
                              hipStream_t stream)
{
    const float* X       = (const float*)d_in[0];
    const float* Wf      = (const float*)d_in[1];
    const float* bvec    = (const float*)d_in[2];
    const float* entries = (const float*)d_in[3];
    const float* gumbel  = (const float*)d_in[4];
    float* out = (float*)d_out;

    float* gavgp = (float*)d_ws;                                   // 2560 B
    unsigned int* gcnt = (unsigned int*)((char*)d_ws + 2560);      // 2560 B
    _Float16* Wh = (_Float16*)((char*)d_ws + 8192);                // 640 KB
    _Float16* Wl = (_Float16*)((char*)d_ws + 8192 + 655360);       // 640 KB

    hipMemsetAsync(d_ws, 0, 8192, stream);
    split16<<<160, 256, 0, stream>>>(Wf, Wh, Wl, 40960);           // 640*512/8
    gemm_cvt<<<1875, 256, 0, stream>>>(X, Wh, Wl, bvec, out + CB_OFF);
    epilogue_kernel<<<1500, 256, 0, stream>>>(X, Wf, bvec, entries, gumbel, out, gavgp, gcnt);
    finalize_kernel<<<1, 640, 0, stream>>>(gavgp, gcnt, out);
}